// Round 9
// baseline (80.224 us; speedup 1.0000x reference)
//
#include <hip/hip_runtime.h>
#include <hip/hip_bf16.h>
#include <math.h>

// (B,T,C,H) = (4,4096,256,64)
#define Bb   4
#define T    4096
#define Cc   256
#define Hh   64
#define BT   (Bb*T)
#define CPB  272             // chunks/batch: sum_{qt<32} ceil((2qt+2)/4)

using f32x4  = __attribute__((ext_vector_type(4))) float;
using f32x16 = __attribute__((ext_vector_type(16))) float;
using short8 = __attribute__((ext_vector_type(8))) short;
using int4v  = __attribute__((ext_vector_type(4))) int;

__device__ __forceinline__ float fexp2(float x) {   // hw v_exp_f32 (2^x)
    return __builtin_amdgcn_exp2f(x);
}
__device__ __forceinline__ ushort f2bf(float f) {
    unsigned u = __builtin_bit_cast(unsigned, f);
    return (ushort)((u + 0x8000u) >> 16);
}
__device__ __forceinline__ float bf2f(ushort u) {
    return __builtin_bit_cast(float, (unsigned)u << 16);
}
// swizzled byte offset, [rows][512B] tile (256 bf16 cols)
__device__ __forceinline__ int swzx(int row, int cb) { return (row<<9) + (cb ^ ((row&7)<<4)); }
// chunks for q-tiles < qt; chunks(qt) = (qt+2)>>1  (CHUNK=4 k-tiles, 128-row q-tiles)
__device__ __forceinline__ int chunk_prefix(int qt) {
    const int a = qt >> 1;
    return (qt & 1) ? (a+1)*(a+1) : a*(a+1);
}

#define GLOAD16(g, l) __builtin_amdgcn_global_load_lds( \
    (const __attribute__((address_space(1))) unsigned*)(g), \
    (__attribute__((address_space(3))) unsigned*)(l), 16, 0, 0)

// ---------------------------------------------------------------------------
// Pack Wq|Wk|Wv -> Wt bf16 [192][256], PRE-SWIZZLED rows (512B); log2e/16 in Wq.
// ---------------------------------------------------------------------------
__global__ __launch_bounds__(256) void wtrans(
    const float* __restrict__ Wq, const float* __restrict__ Wk,
    const float* __restrict__ Wv, ushort* __restrict__ WtG)
{
    __shared__ float wl[256][65];
    const int t = threadIdx.x;
    const int m = blockIdx.x;                  // 0=q 1=k 2=v
    const float* W = (m==0) ? Wq : (m==1) ? Wk : Wv;
    const float scale = (m==0) ? 0.09016844005556021f : 1.0f;  // log2e/16
    for (int idx = t; idx < 4096; idx += 256) {
        const float4 v4 = ((const float4*)W)[idx];
        const int c = idx >> 4;
        const int h = (idx & 15) * 4;
        wl[c][h+0]=v4.x*scale; wl[c][h+1]=v4.y*scale;
        wl[c][h+2]=v4.z*scale; wl[c][h+3]=v4.w*scale;
    }
    __syncthreads();
    const int h  = t & 63;
    const int n  = m*64 + h;
    const int c0 = (t >> 6) * 64;
    for (int c = c0; c < c0 + 64; c += 4) {
        ushort4 o;
        o.x=f2bf(wl[c+0][h]); o.y=f2bf(wl[c+1][h]);
        o.z=f2bf(wl[c+2][h]); o.w=f2bf(wl[c+3][h]);
        *(ushort4*)((char*)WtG + n*512 + ((c*2) ^ ((n&7)<<4))) = o;   // pre-swizzled
    }
}

// ---------------------------------------------------------------------------
// MFMA projection (R7 version): q,k row-major bf16 + vT [b][h][T] bf16.
// W staged in LDS via linear global_load_lds (content pre-swizzled).
// ---------------------------------------------------------------------------
__global__ __launch_bounds__(256) void proj_mfma(
    const float* __restrict__ x, const ushort* __restrict__ WtG,
    ushort* __restrict__ qo, ushort* __restrict__ ko, ushort* __restrict__ vtG)
{
    __shared__ ushort xls[64*256];     // 32KB, swizzled 512B rows
    __shared__ ushort wls[192*256];    // 96KB, content pre-swizzled
    const int t = threadIdx.x, w = t>>6, lane = t&63, g = lane>>4, ln = lane&15;
    const int blk = blockIdx.x;
    const long rowbase = (long)blk * 64;
    const int b    = blk >> 6;
    const int trow = (blk & 63) * 64;

    {   // Wt: 96KB linear global->LDS copy (content already swizzled)
        const char* src = (const char*)WtG + (long)lane*16;
        for (int c = w; c < 96; c += 4)
            GLOAD16(src + c*1024, (char*)wls + c*1024);
    }
    for (int j = 0; j < 16; ++j) {
        const int idx = t + j*256;
        const int row = idx >> 6;
        const int c4  = (idx & 63) * 4;
        const float4 xv = ((const float4*)x)[(rowbase + row)*64 + (c4>>2)];
        ushort4 o; o.x=f2bf(xv.x); o.y=f2bf(xv.y); o.z=f2bf(xv.z); o.w=f2bf(xv.w);
        *(ushort4*)((char*)xls + swzx(row, c4*2)) = o;
    }
    __syncthreads();

    short8 xf[8];
    #pragma unroll
    for (int ks = 0; ks < 8; ++ks)
        xf[ks] = *(const short8*)((const char*)xls + swzx(w*16+ln, ks*64 + g*16));

    #pragma unroll
    for (int nt = 0; nt < 12; ++nt) {
        f32x4 acc = (f32x4){0.f,0.f,0.f,0.f};
        #pragma unroll
        for (int ks = 0; ks < 8; ++ks) {
            const short8 wf = *(const short8*)((const char*)wls + swzx(nt*16+ln, ks*64 + g*16));
            acc = (nt < 8) ? __builtin_amdgcn_mfma_f32_16x16x32_bf16(wf, xf[ks], acc, 0,0,0)
                           : __builtin_amdgcn_mfma_f32_16x16x32_bf16(xf[ks], wf, acc, 0,0,0);
        }
        ushort4 o; o.x=f2bf(acc[0]); o.y=f2bf(acc[1]); o.z=f2bf(acc[2]); o.w=f2bf(acc[3]);
        if (nt < 4) {
            *(ushort4*)(qo + (rowbase + w*16 + ln)*64 + nt*16 + g*4) = o;
        } else if (nt < 8) {
            *(ushort4*)(ko + (rowbase + w*16 + ln)*64 + (nt-4)*16 + g*4) = o;
        } else {
            *(ushort4*)(vtG + ((long)b*64 + (nt-8)*16 + ln)*T + trow + w*16 + g*4) = o;
        }
    }
}

// ---------------------------------------------------------------------------
// Flash attention, 32x32 swapped-QK^T, in-register softmax.
// LDS-FREE / BARRIER-FREE: all MFMA fragments are contiguous 16B loads from
// L2-resident K and V^T. Block = (b, qt[128 rows], chunk of <=4 key-tiles),
// 4 waves x 32 q-rows, per-wave tile bounds. grid = 4*272 = 1088.
// Partials: O bf16 [chunk][128 q][64 h].
// ---------------------------------------------------------------------------
__global__ __launch_bounds__(256) void attn_mfma(
    const ushort* __restrict__ q, const ushort* __restrict__ k,
    const ushort* __restrict__ vt,
    ushort* __restrict__ part_o, float* __restrict__ part_ml)
{
    const int bid = blockIdx.x;
    const int b   = bid & 3;
    const int w2  = (CPB - 1) - (bid >> 2);        // big q-tiles first
    int qt = 0, c = 0;
    {
        int acc = 0;
        for (int qq = 0; qq < 32; ++qq) {
            const int n = (qq + 2) >> 1;
            if (w2 < acc + n) { qt = qq; c = w2 - acc; break; }
            acc += n;
        }
    }
    const int kt0   = c * 4;
    const int ktend = min(2*qt + 1, kt0 + 3);
    const int pid   = b*CPB + chunk_prefix(qt) + c;

    const int t = threadIdx.x, w = t>>6, lane = t&63;
    const int l5 = lane & 31, g5 = lane >> 5;
    const ushort* kB = k  + (long)b*T*64;
    const ushort* vB = vt + (long)b*64*T;

    const int qmin = qt*128 + w*32;        // wave's first q row (in batch)
    const int qrow = qmin + l5;            // this lane's q row
    const int ktend_w = min(ktend, (qmin + 31) >> 6);   // per-wave causal bound

    short8 qf[4];
    {
        const ushort* qp = q + ((long)(b*T + qrow))*64;
        #pragma unroll
        for (int hs = 0; hs < 4; ++hs)
            qf[hs] = *(const short8*)(qp + hs*16 + g5*8);
    }

    f32x16 o0, o1;                          // O^T acc: h-subtiles 0..31, 32..63
    #pragma unroll
    for (int i = 0; i < 16; ++i) { o0[i] = 0.f; o1[i] = 0.f; }
    float mrun = -INFINITY, lpart = 0.f;    // log2-domain m; per-lane l over own keys

    for (int kt = kt0; kt <= ktend_w; ++kt) {
        // ---- S^T = K Q : fragments straight from global (L1/L2-hot) ----
        const ushort* kR = kB + ((long)kt*64 + l5)*64;
        f32x16 s0, s1;
        #pragma unroll
        for (int i = 0; i < 16; ++i) { s0[i] = 0.f; s1[i] = 0.f; }
        __builtin_amdgcn_s_setprio(1);
        #pragma unroll
        for (int hs = 0; hs < 4; ++hs) {
            const short8 kf0 = *(const short8*)(kR + hs*16 + g5*8);
            s0 = __builtin_amdgcn_mfma_f32_32x32x16_bf16(kf0, qf[hs], s0, 0, 0, 0);
            const short8 kf1 = *(const short8*)(kR + 32*64 + hs*16 + g5*8);
            s1 = __builtin_amdgcn_mfma_f32_32x32x16_bf16(kf1, qf[hs], s1, 0, 0, 0);
        }
        __builtin_amdgcn_s_setprio(0);

        if (kt*64 + 63 > qmin) {           // causal mask (diagonal region)
            #pragma unroll
            for (int reg = 0; reg < 16; ++reg) {
                const int kl = (reg&3) + 8*(reg>>2) + 4*g5;
                if (kt*64 + kl      > qrow) s0[reg] = -INFINITY;
                if (kt*64 + 32 + kl > qrow) s1[reg] = -INFINITY;
            }
        }

        // ---- defer-max vote (log2 domain, THR = 11.5 ~ e-domain 8) ----
        bool ok = true;
        #pragma unroll
        for (int r = 0; r < 16; ++r) {
            ok &= (s0[r] <= mrun + 11.5f);
            ok &= (s1[r] <= mrun + 11.5f);
        }
        if (!__all(ok)) {
            float mt = s0[0];
            #pragma unroll
            for (int r = 1; r < 16; ++r) mt = fmaxf(mt, s0[r]);
            #pragma unroll
            for (int r = 0; r < 16; ++r) mt = fmaxf(mt, s1[r]);
            mt = fmaxf(mt, __shfl_xor(mt, 32));      // pair holds other 32 keys
            const float mn = fmaxf(mrun, mt);
            const float corr = fexp2(mrun - mn);     // 0 on first tile
            lpart *= corr;
            #pragma unroll
            for (int r = 0; r < 16; ++r) { o0[r] *= corr; o1[r] *= corr; }
            mrun = mn;
        }

        // ---- P = exp2(S - m), pack bf16 pairs in-register ----
        unsigned u0[8], u1[8];
        #pragma unroll
        for (int i = 0; i < 8; ++i) {
            const float pa = fexp2(s0[2*i+0] - mrun);
            const float pb = fexp2(s0[2*i+1] - mrun);
            lpart += pa + pb;
            u0[i] = (unsigned)f2bf(pa) | ((unsigned)f2bf(pb) << 16);
            const float pc = fexp2(s1[2*i+0] - mrun);
            const float pd = fexp2(s1[2*i+1] - mrun);
            lpart += pc + pd;
            u1[i] = (unsigned)f2bf(pc) | ((unsigned)f2bf(pd) << 16);
        }
        // cross-half exchange: other lane's packs
        unsigned x0[8], x1[8];
        #pragma unroll
        for (int i = 0; i < 8; ++i) {
            x0[i] = (unsigned)__shfl_xor((int)u0[i], 32);
            x1[i] = (unsigned)__shfl_xor((int)u1[i], 32);
        }
        // assemble PV B-fragments: pfrag[ks2] covers keys ks2*16..+15
        int4v pw[4];
        #pragma unroll
        for (int s = 0; s < 2; ++s) {
            pw[s].x   = g5 ? (int)x0[4*s+2] : (int)u0[4*s+0];
            pw[s].y   = g5 ? (int)x0[4*s+3] : (int)u0[4*s+1];
            pw[s].z   = g5 ? (int)u0[4*s+2] : (int)x0[4*s+0];
            pw[s].w   = g5 ? (int)u0[4*s+3] : (int)x0[4*s+1];
            pw[2+s].x = g5 ? (int)x1[4*s+2] : (int)u1[4*s+0];
            pw[2+s].y = g5 ? (int)x1[4*s+3] : (int)u1[4*s+1];
            pw[2+s].z = g5 ? (int)u1[4*s+2] : (int)x1[4*s+0];
            pw[2+s].w = g5 ? (int)u1[4*s+3] : (int)x1[4*s+1];
        }

        // ---- O^T += V^T P : V^T fragments straight from global ----
        const ushort* vR0 = vB + (long)l5*T       + kt*64;
        const ushort* vR1 = vB + (long)(32+l5)*T  + kt*64;
        __builtin_amdgcn_s_setprio(1);
        #pragma unroll
        for (int ks2 = 0; ks2 < 4; ++ks2) {
            const short8 pa = __builtin_bit_cast(short8, pw[ks2]);
            const short8 vf0 = *(const short8*)(vR0 + ks2*16 + g5*8);
            o0 = __builtin_amdgcn_mfma_f32_32x32x16_bf16(vf0, pa, o0, 0, 0, 0);
            const short8 vf1 = *(const short8*)(vR1 + ks2*16 + g5*8);
            o1 = __builtin_amdgcn_mfma_f32_32x32x16_bf16(vf1, pa, o1, 0, 0, 0);
        }
        __builtin_amdgcn_s_setprio(0);
    }

    // ---- epilogue: pair-sum l, write (m,l) + O bf16 partials [q][h] ----
    const float ltot = lpart + __shfl_xor(lpart, 32);
    if (g5 == 0) {
        part_ml[((long)pid*128 + w*32 + l5)*2 + 0] = mrun;
        part_ml[((long)pid*128 + w*32 + l5)*2 + 1] = ltot;
    }
    // o0/o1 reg e of quad rq holds h = e + 8*rq + 4*g5 (o1: +32), q = w*32+l5
    ushort* po = part_o + (long)pid*8192 + (w*32 + l5)*64;
    #pragma unroll
    for (int rq = 0; rq < 4; ++rq) {
        ushort4 a;
        a.x = f2bf(o0[4*rq+0]); a.y = f2bf(o0[4*rq+1]);
        a.z = f2bf(o0[4*rq+2]); a.w = f2bf(o0[4*rq+3]);
        *(ushort4*)(po + 8*rq + 4*g5) = a;
        ushort4 bq;
        bq.x = f2bf(o1[4*rq+0]); bq.y = f2bf(o1[4*rq+1]);
        bq.z = f2bf(o1[4*rq+2]); bq.w = f2bf(o1[4*rq+3]);
        *(ushort4*)(po + 32 + 8*rq + 4*g5) = bq;
    }
}

// ---------------------------------------------------------------------------
// Merge <=16 chunk partials (LSE, log2 domain), write fp32 [q][h] output.
// grid = (b, qt, 32q-slice) = 4*32*4 = 512 blocks, 128 thr (2 waves).
// ---------------------------------------------------------------------------
__global__ __launch_bounds__(128) void attn_merge(
    const ushort* __restrict__ part_o, const float* __restrict__ part_ml,
    float* __restrict__ out)
{
    const int bid = blockIdx.x;
    const int qs  = bid & 3;
    const int qt  = (bid >> 2) & 31;
    const int b   = bid >> 7;
    const int t = threadIdx.x, w = t >> 6, lane = t & 63;
    const int ql = qs*32 + w*16 + (lane >> 2);     // q_local 0..127
    const int h0 = (lane & 3) * 16;
    const int nseg = (qt + 2) >> 1;
    const int base = b*CPB + chunk_prefix(qt);

    float mstar = -INFINITY;
    for (int s = 0; s < nseg; ++s) {
        const float2 ml = *(const float2*)(part_ml + ((long)(base+s)*128 + ql)*2);
        mstar = fmaxf(mstar, ml.x);
    }
    float acc[16];
    #pragma unroll
    for (int i = 0; i < 16; ++i) acc[i] = 0.f;
    float lsum = 0.f;
    for (int s = 0; s < nseg; ++s) {
        const float2 ml = *(const float2*)(part_ml + ((long)(base+s)*128 + ql)*2);
        const float wgt = fexp2(ml.x - mstar);
        lsum += ml.y * wgt;
        const short8* po = (const short8*)(part_o + (long)(base+s)*8192 + ql*64 + h0);
        const short8 a = po[0], c8 = po[1];
        #pragma unroll
        for (int e = 0; e < 8; ++e) {
            acc[e]   += wgt * bf2f((ushort)a[e]);
            acc[8+e] += wgt * bf2f((ushort)c8[e]);
        }
    }
    const float inv = 1.f / lsum;
    float* op = out + ((long)b*T + qt*128 + ql)*64 + h0;
    #pragma unroll
    for (int j = 0; j < 4; ++j)
        ((float4*)op)[j] = make_float4(acc[4*j+0]*inv, acc[4*j+1]*inv,
                                       acc[4*j+2]*inv, acc[4*j+3]*inv);
}

// ---------------------------------------------------------------------------
extern "C" void kernel_launch(void* const* d_in, const int* in_sizes, int n_in,
                              void* d_out, int out_size, void* d_ws, size_t ws_size,
                              hipStream_t stream)
{
    const float* x  = (const float*)d_in[0];
    const float* Wk = (const float*)d_in[1];
    const float* Wq = (const float*)d_in[2];
    const float* Wv = (const float*)d_in[3];

    char* w8 = (char*)d_ws;
    ushort* qb      = (ushort*)(w8);                    // 2 MB
    ushort* kb      = (ushort*)(w8 + (2l<<20));         // 2 MB
    ushort* vt      = (ushort*)(w8 + (4l<<20));         // 2 MB
    ushort* Wt      = (ushort*)(w8 + (6l<<20));         // 96 KB
    ushort* part_o  = (ushort*)(w8 + (7l<<20));         // 1088*16KB = 17.4 MB
    float*  part_ml = (float*) (w8 + (25l<<20));        // 1.1 MB

    wtrans    <<<3,         256, 0, stream>>>(Wq, Wk, Wv, Wt);
    proj_mfma <<<BT/64,     256, 0, stream>>>(x, Wt, qb, kb, vt);
    attn_mfma <<<Bb*CPB,    256, 0, stream>>>(qb, kb, vt, part_o, part_ml);
    attn_merge<<<Bb*32*4,   128, 0, stream>>>(part_o, part_ml, (float*)d_out);
}

// Round 10
// 64.628 us; speedup vs baseline: 1.2413x; 1.2413x over previous
//
#include <hip/hip_runtime.h>
#include <hip/hip_bf16.h>
#include <math.h>

// (B,T,C,H) = (4,4096,256,64)
#define Bb   4
#define T    4096
#define Cc   256
#define Hh   64
#define BT   (Bb*T)
#define CPB  272             // chunks/batch: sum_{qt<32} ceil((2qt+2)/4)

using f32x4  = __attribute__((ext_vector_type(4))) float;
using f32x16 = __attribute__((ext_vector_type(16))) float;
using short8 = __attribute__((ext_vector_type(8))) short;
using int4v  = __attribute__((ext_vector_type(4))) int;

__device__ __forceinline__ float fexp2(float x) {   // hw v_exp_f32 (2^x)
    return __builtin_amdgcn_exp2f(x);
}
__device__ __forceinline__ ushort f2bf(float f) {
    unsigned u = __builtin_bit_cast(unsigned, f);
    return (ushort)((u + 0x8000u) >> 16);
}
__device__ __forceinline__ float bf2f(ushort u) {
    return __builtin_bit_cast(float, (unsigned)u << 16);
}
// swizzled byte offset, [rows][128B] tile (64 bf16 cols)
__device__ __forceinline__ int swzb(int row, int cb) { return (row<<7) + (cb ^ ((row&7)<<4)); }
// swizzled byte offset, [rows][512B] tile (256 bf16 cols)
__device__ __forceinline__ int swzx(int row, int cb) { return (row<<9) + (cb ^ ((row&7)<<4)); }
// chunks for q-tiles < qt; chunks(qt) = (qt+2)>>1  (CHUNK=4 k-tiles, 128-row q-tiles)
__device__ __forceinline__ int chunk_prefix(int qt) {
    const int a = qt >> 1;
    return (qt & 1) ? (a+1)*(a+1) : a*(a+1);
}

#define GLOAD16(g, l) __builtin_amdgcn_global_load_lds( \
    (const __attribute__((address_space(1))) unsigned*)(g), \
    (__attribute__((address_space(3))) unsigned*)(l), 16, 0, 0)

// ---------------------------------------------------------------------------
// Pack Wq|Wk|Wv -> Wt bf16 [192][256], PRE-SWIZZLED rows (512B); log2e/16 in Wq.
// ---------------------------------------------------------------------------
__global__ __launch_bounds__(256) void wtrans(
    const float* __restrict__ Wq, const float* __restrict__ Wk,
    const float* __restrict__ Wv, ushort* __restrict__ WtG)
{
    __shared__ float wl[256][65];
    const int t = threadIdx.x;
    const int m = blockIdx.x;                  // 0=q 1=k 2=v
    const float* W = (m==0) ? Wq : (m==1) ? Wk : Wv;
    const float scale = (m==0) ? 0.09016844005556021f : 1.0f;  // log2e/16
    for (int idx = t; idx < 4096; idx += 256) {
        const float4 v4 = ((const float4*)W)[idx];
        const int c = idx >> 4;
        const int h = (idx & 15) * 4;
        wl[c][h+0]=v4.x*scale; wl[c][h+1]=v4.y*scale;
        wl[c][h+2]=v4.z*scale; wl[c][h+3]=v4.w*scale;
    }
    __syncthreads();
    const int h  = t & 63;
    const int n  = m*64 + h;
    const int c0 = (t >> 6) * 64;
    for (int c = c0; c < c0 + 64; c += 4) {
        ushort4 o;
        o.x=f2bf(wl[c+0][h]); o.y=f2bf(wl[c+1][h]);
        o.z=f2bf(wl[c+2][h]); o.w=f2bf(wl[c+3][h]);
        *(ushort4*)((char*)WtG + n*512 + ((c*2) ^ ((n&7)<<4))) = o;   // pre-swizzled
    }
}

// ---------------------------------------------------------------------------
// MFMA projection (R7 version): q,k row-major bf16 + vT [b][h][T] bf16.
// W staged in LDS via linear global_load_lds (content pre-swizzled).
// ---------------------------------------------------------------------------
__global__ __launch_bounds__(256) void proj_mfma(
    const float* __restrict__ x, const ushort* __restrict__ WtG,
    ushort* __restrict__ qo, ushort* __restrict__ ko, ushort* __restrict__ vtG)
{
    __shared__ ushort xls[64*256];     // 32KB, swizzled 512B rows
    __shared__ ushort wls[192*256];    // 96KB, content pre-swizzled
    const int t = threadIdx.x, w = t>>6, lane = t&63, g = lane>>4, ln = lane&15;
    const int blk = blockIdx.x;
    const long rowbase = (long)blk * 64;
    const int b    = blk >> 6;
    const int trow = (blk & 63) * 64;

    {   // Wt: 96KB linear global->LDS copy (content already swizzled)
        const char* src = (const char*)WtG + (long)lane*16;
        for (int c = w; c < 96; c += 4)
            GLOAD16(src + c*1024, (char*)wls + c*1024);
    }
    for (int j = 0; j < 16; ++j) {
        const int idx = t + j*256;
        const int row = idx >> 6;
        const int c4  = (idx & 63) * 4;
        const float4 xv = ((const float4*)x)[(rowbase + row)*64 + (c4>>2)];
        ushort4 o; o.x=f2bf(xv.x); o.y=f2bf(xv.y); o.z=f2bf(xv.z); o.w=f2bf(xv.w);
        *(ushort4*)((char*)xls + swzx(row, c4*2)) = o;
    }
    __syncthreads();

    short8 xf[8];
    #pragma unroll
    for (int ks = 0; ks < 8; ++ks)
        xf[ks] = *(const short8*)((const char*)xls + swzx(w*16+ln, ks*64 + g*16));

    #pragma unroll
    for (int nt = 0; nt < 12; ++nt) {
        f32x4 acc = (f32x4){0.f,0.f,0.f,0.f};
        #pragma unroll
        for (int ks = 0; ks < 8; ++ks) {
            const short8 wf = *(const short8*)((const char*)wls + swzx(nt*16+ln, ks*64 + g*16));
            acc = (nt < 8) ? __builtin_amdgcn_mfma_f32_16x16x32_bf16(wf, xf[ks], acc, 0,0,0)
                           : __builtin_amdgcn_mfma_f32_16x16x32_bf16(xf[ks], wf, acc, 0,0,0);
        }
        ushort4 o; o.x=f2bf(acc[0]); o.y=f2bf(acc[1]); o.z=f2bf(acc[2]); o.w=f2bf(acc[3]);
        if (nt < 4) {
            *(ushort4*)(qo + (rowbase + w*16 + ln)*64 + nt*16 + g*4) = o;
        } else if (nt < 8) {
            *(ushort4*)(ko + (rowbase + w*16 + ln)*64 + (nt-4)*16 + g*4) = o;
        } else {
            *(ushort4*)(vtG + ((long)b*64 + (nt-8)*16 + ln)*T + trow + w*16 + g*4) = o;
        }
    }
}

// ---------------------------------------------------------------------------
// Flash attention, 32x32 swapped-QK^T, in-register softmax (no P LDS).
// LDS dbuf staging with COUNTED vmcnt + raw barriers (T3/T4): prefetch of
// tile kt+1 stays in flight across the barrier; no vmcnt(0) drain in the
// steady-state loop. Block = (b, qt[128 rows], chunk of <=4 key-tiles),
// 4 waves x 32 q-rows. grid = 4*272 = 1088, 256 thr.
// ---------------------------------------------------------------------------
__global__ __launch_bounds__(256) void attn_mfma(
    const ushort* __restrict__ q, const ushort* __restrict__ k,
    const ushort* __restrict__ vt,
    ushort* __restrict__ part_o, float* __restrict__ part_ml)
{
    __shared__ ushort kls[2][4096];      // K  [key][h], swizzled, dbuf (8KB ea)
    __shared__ ushort vtls[2][4096];     // V^T [h][key], swizzled, dbuf

    const int bid = blockIdx.x;
    const int b   = bid & 3;
    const int w2  = (CPB - 1) - (bid >> 2);        // big q-tiles first
    int qt = 0, c = 0;
    {
        int acc = 0;
        for (int qq = 0; qq < 32; ++qq) {
            const int n = (qq + 2) >> 1;
            if (w2 < acc + n) { qt = qq; c = w2 - acc; break; }
            acc += n;
        }
    }
    const int kt0   = c * 4;
    const int ktend = min(2*qt + 1, kt0 + 3);
    const int ntile = ktend - kt0 + 1;
    const int pid   = b*CPB + chunk_prefix(qt) + c;

    const int t = threadIdx.x, w = t>>6, lane = t&63;
    const int l5 = lane & 31, g5 = lane >> 5;
    const int lrow = lane >> 3;
    const int lc16 = ((lane & 7) ^ lrow) * 16;
    const char* kbase = (const char*)k  + ((long)b*T)*128;
    const char* vbase = (const char*)vt + ((long)b*64)*(long)T*2;

    // 4 gload_lds per wave per tile (2 K + 2 V) — vmcnt counting relies on this
    #define STAGE(bufi, ktile) do { \
        _Pragma("unroll") for (int j = 0; j < 2; ++j) { const int ci = w*2 + j; \
            GLOAD16(kbase + (long)(ktile)*8192 + ci*1024 + lrow*128 + lc16, \
                    (char*)kls[bufi] + ci*1024); \
            GLOAD16(vbase + ((long)(8*ci + lrow))*8192 + (long)(ktile)*128 + lc16, \
                    (char*)vtls[bufi] + ci*1024); \
        } } while(0)

    const int qmin = qt*128 + w*32;        // wave's first q row (in batch)
    const int qrow = qmin + l5;            // this lane's q row

    short8 qf[4];
    {
        const ushort* qp = q + ((long)(b*T + qrow))*64;
        #pragma unroll
        for (int hs = 0; hs < 4; ++hs)
            qf[hs] = *(const short8*)(qp + hs*16 + g5*8);
    }

    f32x16 o0, o1;                          // O^T acc: h-subtiles 0..31, 32..63
    #pragma unroll
    for (int i = 0; i < 16; ++i) { o0[i] = 0.f; o1[i] = 0.f; }
    float mrun = -INFINITY, lpart = 0.f;    // log2-domain m; per-lane l over own keys

    STAGE(0, kt0);
    for (int it = 0; it < ntile; ++it) {
        const int kt  = kt0 + it;
        const int cur = it & 1;

        // prefetch next tile, then wait ONLY for current buffer's 4 loads
        if (it + 1 < ntile) {
            STAGE(cur^1, kt + 1);
            asm volatile("s_waitcnt vmcnt(4)" ::: "memory");
        } else {
            asm volatile("s_waitcnt vmcnt(0)" ::: "memory");
        }
        __builtin_amdgcn_sched_barrier(0);
        __builtin_amdgcn_s_barrier();      // all waves: buf[cur] fully staged
        __builtin_amdgcn_sched_barrier(0);

        if (kt*64 <= qmin + 31) {          // wave not past diagonal
            // ---- S^T = K Q : D[key][q], two 32-key subtiles ----
            f32x16 s0, s1;
            #pragma unroll
            for (int i = 0; i < 16; ++i) { s0[i] = 0.f; s1[i] = 0.f; }
            __builtin_amdgcn_s_setprio(1);
            #pragma unroll
            for (int hs = 0; hs < 4; ++hs) {
                const short8 kf0 = *(const short8*)((const char*)kls[cur] + swzb(l5,    hs*32 + g5*16));
                s0 = __builtin_amdgcn_mfma_f32_32x32x16_bf16(kf0, qf[hs], s0, 0, 0, 0);
                const short8 kf1 = *(const short8*)((const char*)kls[cur] + swzb(32+l5, hs*32 + g5*16));
                s1 = __builtin_amdgcn_mfma_f32_32x32x16_bf16(kf1, qf[hs], s1, 0, 0, 0);
            }
            __builtin_amdgcn_s_setprio(0);

            if (kt*64 + 63 > qmin) {       // causal mask (diagonal region)
                #pragma unroll
                for (int reg = 0; reg < 16; ++reg) {
                    const int kl = (reg&3) + 8*(reg>>2) + 4*g5;
                    if (kt*64 + kl      > qrow) s0[reg] = -INFINITY;
                    if (kt*64 + 32 + kl > qrow) s1[reg] = -INFINITY;
                }
            }

            // ---- defer-max vote (log2 domain, THR = 11.5 ~ e-domain 8) ----
            bool ok = true;
            #pragma unroll
            for (int r = 0; r < 16; ++r) {
                ok &= (s0[r] <= mrun + 11.5f);
                ok &= (s1[r] <= mrun + 11.5f);
            }
            if (!__all(ok)) {
                float mt = s0[0];
                #pragma unroll
                for (int r = 1; r < 16; ++r) mt = fmaxf(mt, s0[r]);
                #pragma unroll
                for (int r = 0; r < 16; ++r) mt = fmaxf(mt, s1[r]);
                mt = fmaxf(mt, __shfl_xor(mt, 32));      // pair holds other 32 keys
                const float mn = fmaxf(mrun, mt);
                const float corr = fexp2(mrun - mn);     // 0 on first tile
                lpart *= corr;
                #pragma unroll
                for (int r = 0; r < 16; ++r) { o0[r] *= corr; o1[r] *= corr; }
                mrun = mn;
            }

            // ---- P = exp2(S - m), pack bf16 pairs in-register ----
            unsigned u0[8], u1[8];
            #pragma unroll
            for (int i = 0; i < 8; ++i) {
                const float pa = fexp2(s0[2*i+0] - mrun);
                const float pb = fexp2(s0[2*i+1] - mrun);
                lpart += pa + pb;
                u0[i] = (unsigned)f2bf(pa) | ((unsigned)f2bf(pb) << 16);
                const float pc = fexp2(s1[2*i+0] - mrun);
                const float pd = fexp2(s1[2*i+1] - mrun);
                lpart += pc + pd;
                u1[i] = (unsigned)f2bf(pc) | ((unsigned)f2bf(pd) << 16);
            }
            // cross-half exchange: other lane's packs
            unsigned x0[8], x1[8];
            #pragma unroll
            for (int i = 0; i < 8; ++i) {
                x0[i] = (unsigned)__shfl_xor((int)u0[i], 32);
                x1[i] = (unsigned)__shfl_xor((int)u1[i], 32);
            }
            // assemble PV B-fragments: pfrag[ks2] covers keys ks2*16..+15
            int4v pw[4];
            #pragma unroll
            for (int s = 0; s < 2; ++s) {
                pw[s].x   = g5 ? (int)x0[4*s+2] : (int)u0[4*s+0];
                pw[s].y   = g5 ? (int)x0[4*s+3] : (int)u0[4*s+1];
                pw[s].z   = g5 ? (int)u0[4*s+2] : (int)x0[4*s+0];
                pw[s].w   = g5 ? (int)u0[4*s+3] : (int)x0[4*s+1];
                pw[2+s].x = g5 ? (int)x1[4*s+2] : (int)u1[4*s+0];
                pw[2+s].y = g5 ? (int)x1[4*s+3] : (int)u1[4*s+1];
                pw[2+s].z = g5 ? (int)u1[4*s+2] : (int)x1[4*s+0];
                pw[2+s].w = g5 ? (int)u1[4*s+3] : (int)x1[4*s+1];
            }

            // ---- O^T += V^T P : D[h][q] ----
            __builtin_amdgcn_s_setprio(1);
            #pragma unroll
            for (int ks2 = 0; ks2 < 4; ++ks2) {
                const short8 pa = __builtin_bit_cast(short8, pw[ks2]);
                const short8 vf0 = *(const short8*)((const char*)vtls[cur] + swzb(l5,    ks2*32 + g5*16));
                o0 = __builtin_amdgcn_mfma_f32_32x32x16_bf16(vf0, pa, o0, 0, 0, 0);
                const short8 vf1 = *(const short8*)((const char*)vtls[cur] + swzb(32+l5, ks2*32 + g5*16));
                o1 = __builtin_amdgcn_mfma_f32_32x32x16_bf16(vf1, pa, o1, 0, 0, 0);
            }
            __builtin_amdgcn_s_setprio(0);
        }

        __builtin_amdgcn_sched_barrier(0);
        __builtin_amdgcn_s_barrier();      // all reads of buf[cur] done before
        __builtin_amdgcn_sched_barrier(0); // next iter's STAGE overwrites it
    }
    #undef STAGE

    // ---- epilogue: pair-sum l, write (m,l) + O bf16 partials [q][h] ----
    const float ltot = lpart + __shfl_xor(lpart, 32);
    if (g5 == 0) {
        part_ml[((long)pid*128 + w*32 + l5)*2 + 0] = mrun;
        part_ml[((long)pid*128 + w*32 + l5)*2 + 1] = ltot;
    }
    // o0/o1 reg e of quad rq holds h = e + 8*rq + 4*g5 (o1: +32), q = w*32+l5
    ushort* po = part_o + (long)pid*8192 + (w*32 + l5)*64;
    #pragma unroll
    for (int rq = 0; rq < 4; ++rq) {
        ushort4 a;
        a.x = f2bf(o0[4*rq+0]); a.y = f2bf(o0[4*rq+1]);
        a.z = f2bf(o0[4*rq+2]); a.w = f2bf(o0[4*rq+3]);
        *(ushort4*)(po + 8*rq + 4*g5) = a;
        ushort4 bq;
        bq.x = f2bf(o1[4*rq+0]); bq.y = f2bf(o1[4*rq+1]);
        bq.z = f2bf(o1[4*rq+2]); bq.w = f2bf(o1[4*rq+3]);
        *(ushort4*)(po + 32 + 8*rq + 4*g5) = bq;
    }
}

// ---------------------------------------------------------------------------
// Merge <=16 chunk partials (LSE, log2 domain), write fp32 [q][h] output.
// grid = (b, qt, 32q-slice) = 4*32*4 = 512 blocks, 128 thr (2 waves).
// ---------------------------------------------------------------------------
__global__ __launch_bounds__(128) void attn_merge(
    const ushort* __restrict__ part_o, const float* __restrict__ part_ml,
    float* __restrict__ out)
{
    const int bid = blockIdx.x;
    const int qs  = bid & 3;
    const int qt  = (bid >> 2) & 31;
    const int b   = bid >> 7;
    const int t = threadIdx.x, w = t >> 6, lane = t & 63;
    const int ql = qs*32 + w*16 + (lane >> 2);     // q_local 0..127
    const int h0 = (lane & 3) * 16;
    const int nseg = (qt + 2) >> 1;
    const int base = b*CPB + chunk_prefix(qt);

    float mstar = -INFINITY;
    for (int s = 0; s < nseg; ++s) {
        const float2 ml = *(const float2*)(part_ml + ((long)(base+s)*128 + ql)*2);
        mstar = fmaxf(mstar, ml.x);
    }
    float acc[16];
    #pragma unroll
    for (int i = 0; i < 16; ++i) acc[i] = 0.f;
    float lsum = 0.f;
    for (int s = 0; s < nseg; ++s) {
        const float2 ml = *(const float2*)(part_ml + ((long)(base+s)*128 + ql)*2);
        const float wgt = fexp2(ml.x - mstar);
        lsum += ml.y * wgt;
        const short8* po = (const short8*)(part_o + (long)(base+s)*8192 + ql*64 + h0);
        const short8 a = po[0], c8 = po[1];
        #pragma unroll
        for (int e = 0; e < 8; ++e) {
            acc[e]   += wgt * bf2f((ushort)a[e]);
            acc[8+e] += wgt * bf2f((ushort)c8[e]);
        }
    }
    const float inv = 1.f / lsum;
    float* op = out + ((long)b*T + qt*128 + ql)*64 + h0;
    #pragma unroll
    for (int j = 0; j < 4; ++j)
        ((float4*)op)[j] = make_float4(acc[4*j+0]*inv, acc[4*j+1]*inv,
                                       acc[4*j+2]*inv, acc[4*j+3]*inv);
}

// ---------------------------------------------------------------------------
extern "C" void kernel_launch(void* const* d_in, const int* in_sizes, int n_in,
                              void* d_out, int out_size, void* d_ws, size_t ws_size,
                              hipStream_t stream)
{
    const float* x  = (const float*)d_in[0];
    const float* Wk = (const float*)d_in[1];
    const float* Wq = (const float*)d_in[2];
    const float* Wv = (const float*)d_in[3];

    char* w8 = (char*)d_ws;
    ushort* qb      = (ushort*)(w8);                    // 2 MB
    ushort* kb      = (ushort*)(w8 + (2l<<20));         // 2 MB
    ushort* vt      = (ushort*)(w8 + (4l<<20));         // 2 MB
    ushort* Wt      = (ushort*)(w8 + (6l<<20));         // 96 KB
    ushort* part_o  = (ushort*)(w8 + (7l<<20));         // 1088*16KB = 17.4 MB
    float*  part_ml = (float*) (w8 + (25l<<20));        // 1.1 MB

    wtrans    <<<3,         256, 0, stream>>>(Wq, Wk, Wv, Wt);
    proj_mfma <<<BT/64,     256, 0, stream>>>(x, Wt, qb, kb, vt);
    attn_mfma <<<Bb*CPB,    256, 0, stream>>>(qb, kb, vt, part_o, part_ml);
    attn_merge<<<Bb*32*4,   128, 0, stream>>>(part_o, part_ml, (float*)d_out);
}

// Round 11
// 64.579 us; speedup vs baseline: 1.2423x; 1.0008x over previous
//
#include <hip/hip_runtime.h>
#include <hip/hip_bf16.h>
#include <math.h>

// (B,T,C,H) = (4,4096,256,64)
#define Bb   4
#define T    4096
#define Cc   256
#define Hh   64
#define BT   (Bb*T)
#define CPB  272             // chunks/batch: sum_{qt<32} ceil((2qt+2)/4)

using f32x4  = __attribute__((ext_vector_type(4))) float;
using f32x16 = __attribute__((ext_vector_type(16))) float;
using short8 = __attribute__((ext_vector_type(8))) short;
using int4v  = __attribute__((ext_vector_type(4))) int;

__device__ __forceinline__ float fexp2(float x) {   // hw v_exp_f32 (2^x)
    return __builtin_amdgcn_exp2f(x);
}
__device__ __forceinline__ ushort f2bf(float f) {
    unsigned u = __builtin_bit_cast(unsigned, f);
    return (ushort)((u + 0x8000u) >> 16);
}
__device__ __forceinline__ float bf2f(ushort u) {
    return __builtin_bit_cast(float, (unsigned)u << 16);
}
// swizzled byte offset, [rows][128B] tile (64 bf16 cols)
__device__ __forceinline__ int swzb(int row, int cb) { return (row<<7) + (cb ^ ((row&7)<<4)); }
// swizzled byte offset, [rows][512B] tile (256 bf16 cols)
__device__ __forceinline__ int swzx(int row, int cb) { return (row<<9) + (cb ^ ((row&7)<<4)); }
// chunks for q-tiles < qt; chunks(qt) = (qt+2)>>1  (CHUNK=4 k-tiles, 128-row q-tiles)
__device__ __forceinline__ int chunk_prefix(int qt) {
    const int a = qt >> 1;
    return (qt & 1) ? (a+1)*(a+1) : a*(a+1);
}

#define GLOAD16(g, l) __builtin_amdgcn_global_load_lds( \
    (const __attribute__((address_space(1))) unsigned*)(g), \
    (__attribute__((address_space(3))) unsigned*)(l), 16, 0, 0)

// ---------------------------------------------------------------------------
// Pack Wq|Wk|Wv -> Wt bf16 [192][256], PRE-SWIZZLED rows (512B); log2e/16 in Wq.
// ---------------------------------------------------------------------------
__global__ __launch_bounds__(256) void wtrans(
    const float* __restrict__ Wq, const float* __restrict__ Wk,
    const float* __restrict__ Wv, ushort* __restrict__ WtG)
{
    __shared__ float wl[256][65];
    const int t = threadIdx.x;
    const int m = blockIdx.x;                  // 0=q 1=k 2=v
    const float* W = (m==0) ? Wq : (m==1) ? Wk : Wv;
    const float scale = (m==0) ? 0.09016844005556021f : 1.0f;  // log2e/16
    for (int idx = t; idx < 4096; idx += 256) {
        const float4 v4 = ((const float4*)W)[idx];
        const int c = idx >> 4;
        const int h = (idx & 15) * 4;
        wl[c][h+0]=v4.x*scale; wl[c][h+1]=v4.y*scale;
        wl[c][h+2]=v4.z*scale; wl[c][h+3]=v4.w*scale;
    }
    __syncthreads();
    const int h  = t & 63;
    const int n  = m*64 + h;
    const int c0 = (t >> 6) * 64;
    for (int c = c0; c < c0 + 64; c += 4) {
        ushort4 o;
        o.x=f2bf(wl[c+0][h]); o.y=f2bf(wl[c+1][h]);
        o.z=f2bf(wl[c+2][h]); o.w=f2bf(wl[c+3][h]);
        *(ushort4*)((char*)WtG + n*512 + ((c*2) ^ ((n&7)<<4))) = o;   // pre-swizzled
    }
}

// ---------------------------------------------------------------------------
// MFMA projection (R7 version): q,k row-major bf16 + vT [b][h][T] bf16.
// W staged in LDS via linear global_load_lds (content pre-swizzled).
// ---------------------------------------------------------------------------
__global__ __launch_bounds__(256) void proj_mfma(
    const float* __restrict__ x, const ushort* __restrict__ WtG,
    ushort* __restrict__ qo, ushort* __restrict__ ko, ushort* __restrict__ vtG)
{
    __shared__ ushort xls[64*256];     // 32KB, swizzled 512B rows
    __shared__ ushort wls[192*256];    // 96KB, content pre-swizzled
    const int t = threadIdx.x, w = t>>6, lane = t&63, g = lane>>4, ln = lane&15;
    const int blk = blockIdx.x;
    const long rowbase = (long)blk * 64;
    const int b    = blk >> 6;
    const int trow = (blk & 63) * 64;

    {   // Wt: 96KB linear global->LDS copy (content already swizzled)
        const char* src = (const char*)WtG + (long)lane*16;
        for (int c = w; c < 96; c += 4)
            GLOAD16(src + c*1024, (char*)wls + c*1024);
    }
    for (int j = 0; j < 16; ++j) {
        const int idx = t + j*256;
        const int row = idx >> 6;
        const int c4  = (idx & 63) * 4;
        const float4 xv = ((const float4*)x)[(rowbase + row)*64 + (c4>>2)];
        ushort4 o; o.x=f2bf(xv.x); o.y=f2bf(xv.y); o.z=f2bf(xv.z); o.w=f2bf(xv.w);
        *(ushort4*)((char*)xls + swzx(row, c4*2)) = o;
    }
    __syncthreads();

    short8 xf[8];
    #pragma unroll
    for (int ks = 0; ks < 8; ++ks)
        xf[ks] = *(const short8*)((const char*)xls + swzx(w*16+ln, ks*64 + g*16));

    #pragma unroll
    for (int nt = 0; nt < 12; ++nt) {
        f32x4 acc = (f32x4){0.f,0.f,0.f,0.f};
        #pragma unroll
        for (int ks = 0; ks < 8; ++ks) {
            const short8 wf = *(const short8*)((const char*)wls + swzx(nt*16+ln, ks*64 + g*16));
            acc = (nt < 8) ? __builtin_amdgcn_mfma_f32_16x16x32_bf16(wf, xf[ks], acc, 0,0,0)
                           : __builtin_amdgcn_mfma_f32_16x16x32_bf16(xf[ks], wf, acc, 0,0,0);
        }
        ushort4 o; o.x=f2bf(acc[0]); o.y=f2bf(acc[1]); o.z=f2bf(acc[2]); o.w=f2bf(acc[3]);
        if (nt < 4) {
            *(ushort4*)(qo + (rowbase + w*16 + ln)*64 + nt*16 + g*4) = o;
        } else if (nt < 8) {
            *(ushort4*)(ko + (rowbase + w*16 + ln)*64 + (nt-4)*16 + g*4) = o;
        } else {
            *(ushort4*)(vtG + ((long)b*64 + (nt-8)*16 + ln)*T + trow + w*16 + g*4) = o;
        }
    }
}

// ---------------------------------------------------------------------------
// Flash attention, 32x32 swapped-QK^T, in-register softmax (no P LDS).
// LDS dbuf staging with COUNTED vmcnt + raw barriers (T3/T4): prefetch of
// tile kt+1 stays in flight across the barrier; no vmcnt(0) drain in the
// steady-state loop. Block = (b, qt[128 rows], chunk of <=4 key-tiles),
// 4 waves x 32 q-rows. grid = 4*272 = 1088, 256 thr.
// ---------------------------------------------------------------------------
__global__ __launch_bounds__(256) void attn_mfma(
    const ushort* __restrict__ q, const ushort* __restrict__ k,
    const ushort* __restrict__ vt,
    ushort* __restrict__ part_o, float* __restrict__ part_ml)
{
    __shared__ ushort kls[2][4096];      // K  [key][h], swizzled, dbuf (8KB ea)
    __shared__ ushort vtls[2][4096];     // V^T [h][key], swizzled, dbuf

    const int bid = blockIdx.x;
    const int b   = bid & 3;
    const int w2  = (CPB - 1) - (bid >> 2);        // big q-tiles first
    int qt = 0, c = 0;
    {
        int acc = 0;
        for (int qq = 0; qq < 32; ++qq) {
            const int n = (qq + 2) >> 1;
            if (w2 < acc + n) { qt = qq; c = w2 - acc; break; }
            acc += n;
        }
    }
    const int kt0   = c * 4;
    const int ktend = min(2*qt + 1, kt0 + 3);
    const int ntile = ktend - kt0 + 1;
    const int pid   = b*CPB + chunk_prefix(qt) + c;

    const int t = threadIdx.x, w = t>>6, lane = t&63;
    const int l5 = lane & 31, g5 = lane >> 5;
    const int lrow = lane >> 3;
    const int lc16 = ((lane & 7) ^ lrow) * 16;
    const char* kbase = (const char*)k  + ((long)b*T)*128;
    const char* vbase = (const char*)vt + ((long)b*64)*(long)T*2;

    // 4 gload_lds per wave per tile (2 K + 2 V) — vmcnt counting relies on this
    #define STAGE(bufi, ktile) do { \
        _Pragma("unroll") for (int j = 0; j < 2; ++j) { const int ci = w*2 + j; \
            GLOAD16(kbase + (long)(ktile)*8192 + ci*1024 + lrow*128 + lc16, \
                    (char*)kls[bufi] + ci*1024); \
            GLOAD16(vbase + ((long)(8*ci + lrow))*8192 + (long)(ktile)*128 + lc16, \
                    (char*)vtls[bufi] + ci*1024); \
        } } while(0)

    const int qmin = qt*128 + w*32;        // wave's first q row (in batch)
    const int qrow = qmin + l5;            // this lane's q row

    short8 qf[4];
    {
        const ushort* qp = q + ((long)(b*T + qrow))*64;
        #pragma unroll
        for (int hs = 0; hs < 4; ++hs)
            qf[hs] = *(const short8*)(qp + hs*16 + g5*8);
    }

    f32x16 o0, o1;                          // O^T acc: h-subtiles 0..31, 32..63
    #pragma unroll
    for (int i = 0; i < 16; ++i) { o0[i] = 0.f; o1[i] = 0.f; }
    float mrun = -INFINITY, lpart = 0.f;    // log2-domain m; per-lane l over own keys

    STAGE(0, kt0);
    for (int it = 0; it < ntile; ++it) {
        const int kt  = kt0 + it;
        const int cur = it & 1;

        // prefetch next tile, then wait ONLY for current buffer's 4 loads
        if (it + 1 < ntile) {
            STAGE(cur^1, kt + 1);
            asm volatile("s_waitcnt vmcnt(4)" ::: "memory");
        } else {
            asm volatile("s_waitcnt vmcnt(0)" ::: "memory");
        }
        __builtin_amdgcn_sched_barrier(0);
        __builtin_amdgcn_s_barrier();      // all waves: buf[cur] fully staged
        __builtin_amdgcn_sched_barrier(0);

        if (kt*64 <= qmin + 31) {          // wave not past diagonal
            // ---- S^T = K Q : D[key][q], two 32-key subtiles ----
            f32x16 s0, s1;
            #pragma unroll
            for (int i = 0; i < 16; ++i) { s0[i] = 0.f; s1[i] = 0.f; }
            __builtin_amdgcn_s_setprio(1);
            #pragma unroll
            for (int hs = 0; hs < 4; ++hs) {
                const short8 kf0 = *(const short8*)((const char*)kls[cur] + swzb(l5,    hs*32 + g5*16));
                s0 = __builtin_amdgcn_mfma_f32_32x32x16_bf16(kf0, qf[hs], s0, 0, 0, 0);
                const short8 kf1 = *(const short8*)((const char*)kls[cur] + swzb(32+l5, hs*32 + g5*16));
                s1 = __builtin_amdgcn_mfma_f32_32x32x16_bf16(kf1, qf[hs], s1, 0, 0, 0);
            }
            __builtin_amdgcn_s_setprio(0);

            if (kt*64 + 63 > qmin) {       // causal mask (diagonal region)
                #pragma unroll
                for (int reg = 0; reg < 16; ++reg) {
                    const int kl = (reg&3) + 8*(reg>>2) + 4*g5;
                    if (kt*64 + kl      > qrow) s0[reg] = -INFINITY;
                    if (kt*64 + 32 + kl > qrow) s1[reg] = -INFINITY;
                }
            }

            // ---- defer-max vote (log2 domain, THR = 11.5 ~ e-domain 8) ----
            bool ok = true;
            #pragma unroll
            for (int r = 0; r < 16; ++r) {
                ok &= (s0[r] <= mrun + 11.5f);
                ok &= (s1[r] <= mrun + 11.5f);
            }
            if (!__all(ok)) {
                float mt = s0[0];
                #pragma unroll
                for (int r = 1; r < 16; ++r) mt = fmaxf(mt, s0[r]);
                #pragma unroll
                for (int r = 0; r < 16; ++r) mt = fmaxf(mt, s1[r]);
                mt = fmaxf(mt, __shfl_xor(mt, 32));      // pair holds other 32 keys
                const float mn = fmaxf(mrun, mt);
                const float corr = fexp2(mrun - mn);     // 0 on first tile
                lpart *= corr;
                #pragma unroll
                for (int r = 0; r < 16; ++r) { o0[r] *= corr; o1[r] *= corr; }
                mrun = mn;
            }

            // ---- P = exp2(S - m), pack bf16 pairs in-register ----
            unsigned u0[8], u1[8];
            #pragma unroll
            for (int i = 0; i < 8; ++i) {
                const float pa = fexp2(s0[2*i+0] - mrun);
                const float pb = fexp2(s0[2*i+1] - mrun);
                lpart += pa + pb;
                u0[i] = (unsigned)f2bf(pa) | ((unsigned)f2bf(pb) << 16);
                const float pc = fexp2(s1[2*i+0] - mrun);
                const float pd = fexp2(s1[2*i+1] - mrun);
                lpart += pc + pd;
                u1[i] = (unsigned)f2bf(pc) | ((unsigned)f2bf(pd) << 16);
            }
            // cross-half exchange: other lane's packs
            unsigned x0[8], x1[8];
            #pragma unroll
            for (int i = 0; i < 8; ++i) {
                x0[i] = (unsigned)__shfl_xor((int)u0[i], 32);
                x1[i] = (unsigned)__shfl_xor((int)u1[i], 32);
            }
            // assemble PV B-fragments: pfrag[ks2] covers keys ks2*16..+15
            int4v pw[4];
            #pragma unroll
            for (int s = 0; s < 2; ++s) {
                pw[s].x   = g5 ? (int)x0[4*s+2] : (int)u0[4*s+0];
                pw[s].y   = g5 ? (int)x0[4*s+3] : (int)u0[4*s+1];
                pw[s].z   = g5 ? (int)u0[4*s+2] : (int)x0[4*s+0];
                pw[s].w   = g5 ? (int)u0[4*s+3] : (int)x0[4*s+1];
                pw[2+s].x = g5 ? (int)x1[4*s+2] : (int)u1[4*s+0];
                pw[2+s].y = g5 ? (int)x1[4*s+3] : (int)u1[4*s+1];
                pw[2+s].z = g5 ? (int)u1[4*s+2] : (int)x1[4*s+0];
                pw[2+s].w = g5 ? (int)u1[4*s+3] : (int)x1[4*s+1];
            }

            // ---- O^T += V^T P : D[h][q] ----
            __builtin_amdgcn_s_setprio(1);
            #pragma unroll
            for (int ks2 = 0; ks2 < 4; ++ks2) {
                const short8 pa = __builtin_bit_cast(short8, pw[ks2]);
                const short8 vf0 = *(const short8*)((const char*)vtls[cur] + swzb(l5,    ks2*32 + g5*16));
                o0 = __builtin_amdgcn_mfma_f32_32x32x16_bf16(vf0, pa, o0, 0, 0, 0);
                const short8 vf1 = *(const short8*)((const char*)vtls[cur] + swzb(32+l5, ks2*32 + g5*16));
                o1 = __builtin_amdgcn_mfma_f32_32x32x16_bf16(vf1, pa, o1, 0, 0, 0);
            }
            __builtin_amdgcn_s_setprio(0);
        }

        __builtin_amdgcn_sched_barrier(0);
        __builtin_amdgcn_s_barrier();      // all reads of buf[cur] done before
        __builtin_amdgcn_sched_barrier(0); // next iter's STAGE overwrites it
    }
    #undef STAGE

    // ---- epilogue: pair-sum l, write (m,l) + O bf16 partials [q][h] ----
    const float ltot = lpart + __shfl_xor(lpart, 32);
    if (g5 == 0) {
        part_ml[((long)pid*128 + w*32 + l5)*2 + 0] = mrun;
        part_ml[((long)pid*128 + w*32 + l5)*2 + 1] = ltot;
    }
    // o0/o1 reg e of quad rq holds h = e + 8*rq + 4*g5 (o1: +32), q = w*32+l5
    ushort* po = part_o + (long)pid*8192 + (w*32 + l5)*64;
    #pragma unroll
    for (int rq = 0; rq < 4; ++rq) {
        ushort4 a;
        a.x = f2bf(o0[4*rq+0]); a.y = f2bf(o0[4*rq+1]);
        a.z = f2bf(o0[4*rq+2]); a.w = f2bf(o0[4*rq+3]);
        *(ushort4*)(po + 8*rq + 4*g5) = a;
        ushort4 bq;
        bq.x = f2bf(o1[4*rq+0]); bq.y = f2bf(o1[4*rq+1]);
        bq.z = f2bf(o1[4*rq+2]); bq.w = f2bf(o1[4*rq+3]);
        *(ushort4*)(po + 32 + 8*rq + 4*g5) = bq;
    }
}

// ---------------------------------------------------------------------------
// Merge <=16 chunk partials (LSE, log2 domain), write fp32 [q][h] output.
// grid = (b, qt, 32q-slice) = 4*32*4 = 512 blocks, 128 thr (2 waves).
// ---------------------------------------------------------------------------
__global__ __launch_bounds__(128) void attn_merge(
    const ushort* __restrict__ part_o, const float* __restrict__ part_ml,
    float* __restrict__ out)
{
    const int bid = blockIdx.x;
    const int qs  = bid & 3;
    const int qt  = (bid >> 2) & 31;
    const int b   = bid >> 7;
    const int t = threadIdx.x, w = t >> 6, lane = t & 63;
    const int ql = qs*32 + w*16 + (lane >> 2);     // q_local 0..127
    const int h0 = (lane & 3) * 16;
    const int nseg = (qt + 2) >> 1;
    const int base = b*CPB + chunk_prefix(qt);

    float mstar = -INFINITY;
    for (int s = 0; s < nseg; ++s) {
        const float2 ml = *(const float2*)(part_ml + ((long)(base+s)*128 + ql)*2);
        mstar = fmaxf(mstar, ml.x);
    }
    float acc[16];
    #pragma unroll
    for (int i = 0; i < 16; ++i) acc[i] = 0.f;
    float lsum = 0.f;
    for (int s = 0; s < nseg; ++s) {
        const float2 ml = *(const float2*)(part_ml + ((long)(base+s)*128 + ql)*2);
        const float wgt = fexp2(ml.x - mstar);
        lsum += ml.y * wgt;
        const short8* po = (const short8*)(part_o + (long)(base+s)*8192 + ql*64 + h0);
        const short8 a = po[0], c8 = po[1];
        #pragma unroll
        for (int e = 0; e < 8; ++e) {
            acc[e]   += wgt * bf2f((ushort)a[e]);
            acc[8+e] += wgt * bf2f((ushort)c8[e]);
        }
    }
    const float inv = 1.f / lsum;
    float* op = out + ((long)b*T + qt*128 + ql)*64 + h0;
    #pragma unroll
    for (int j = 0; j < 4; ++j)
        ((float4*)op)[j] = make_float4(acc[4*j+0]*inv, acc[4*j+1]*inv,
                                       acc[4*j+2]*inv, acc[4*j+3]*inv);
}

// ---------------------------------------------------------------------------
extern "C" void kernel_launch(void* const* d_in, const int* in_sizes, int n_in,
                              void* d_out, int out_size, void* d_ws, size_t ws_size,
                              hipStream_t stream)
{
    const float* x  = (const float*)d_in[0];
    const float* Wk = (const float*)d_in[1];
    const float* Wq = (const float*)d_in[2];
    const float* Wv = (const float*)d_in[3];

    char* w8 = (char*)d_ws;
    ushort* qb      = (ushort*)(w8);                    // 2 MB
    ushort* kb      = (ushort*)(w8 + (2l<<20));         // 2 MB
    ushort* vt      = (ushort*)(w8 + (4l<<20));         // 2 MB
    ushort* Wt      = (ushort*)(w8 + (6l<<20));         // 96 KB
    ushort* part_o  = (ushort*)(w8 + (7l<<20));         // 1088*16KB = 17.4 MB
    float*  part_ml = (float*) (w8 + (25l<<20));        // 1.1 MB

    wtrans    <<<3,         256, 0, stream>>>(Wq, Wk, Wv, Wt);
    proj_mfma <<<BT/64,     256, 0, stream>>>(x, Wt, qb, kb, vt);
    attn_mfma <<<Bb*CPB,    256, 0, stream>>>(qb, kb, vt, part_o, part_ml);
    attn_merge<<<Bb*32*4,   128, 0, stream>>>(part_o, part_ml, (float*)d_out);
}

// Round 12
// 59.720 us; speedup vs baseline: 1.3433x; 1.0814x over previous
//
#include <hip/hip_runtime.h>
#include <hip/hip_bf16.h>
#include <math.h>

// (B,T,C,H) = (4,4096,256,64)
#define Bb   4
#define T    4096
#define Cc   256
#define Hh   64
#define BT   (Bb*T)
#define CPB  272             // chunks/batch: sum_{qt<32} ceil((2qt+2)/4)

using f32x4  = __attribute__((ext_vector_type(4))) float;
using f32x16 = __attribute__((ext_vector_type(16))) float;
using short8 = __attribute__((ext_vector_type(8))) short;
using int4v  = __attribute__((ext_vector_type(4))) int;

__device__ __forceinline__ float fexp2(float x) {   // hw v_exp_f32 (2^x)
    return __builtin_amdgcn_exp2f(x);
}
__device__ __forceinline__ unsigned fbits(float f) {
    return __builtin_bit_cast(unsigned, f);
}
__device__ __forceinline__ ushort f2bf(float f) {   // round-to-nearest-ish
    return (ushort)((fbits(f) + 0x8000u) >> 16);
}
// pack two f32 -> u32 of 2 bf16 by TRUNCATION (lo in low half)
__device__ __forceinline__ unsigned pkbf(float lo, float hi) {
    return (fbits(hi) & 0xffff0000u) | (fbits(lo) >> 16);
}
__device__ __forceinline__ float bf2f(ushort u) {
    return __builtin_bit_cast(float, (unsigned)u << 16);
}
// swizzled byte offset, [rows][128B] tile (64 bf16 cols)
__device__ __forceinline__ int swzb(int row, int cb) { return (row<<7) + (cb ^ ((row&7)<<4)); }
// swizzled byte offset, [rows][512B] tile (256 bf16 cols)
__device__ __forceinline__ int swzx(int row, int cb) { return (row<<9) + (cb ^ ((row&7)<<4)); }
// chunks for q-tiles < qt; chunks(qt) = (qt+2)>>1  (CHUNK=4 k-tiles, 128-row q-tiles)
__device__ __forceinline__ int chunk_prefix(int qt) {
    const int a = qt >> 1;
    return (qt & 1) ? (a+1)*(a+1) : a*(a+1);
}

#define GLOAD16(g, l) __builtin_amdgcn_global_load_lds( \
    (const __attribute__((address_space(1))) unsigned*)(g), \
    (__attribute__((address_space(3))) unsigned*)(l), 16, 0, 0)

// ---------------------------------------------------------------------------
// Pack Wq|Wk|Wv -> Wt bf16 [192][256], PRE-SWIZZLED rows (512B); log2e/16 in Wq.
// ---------------------------------------------------------------------------
__global__ __launch_bounds__(256) void wtrans(
    const float* __restrict__ Wq, const float* __restrict__ Wk,
    const float* __restrict__ Wv, ushort* __restrict__ WtG)
{
    __shared__ float wl[256][65];
    const int t = threadIdx.x;
    const int m = blockIdx.x;                  // 0=q 1=k 2=v
    const float* W = (m==0) ? Wq : (m==1) ? Wk : Wv;
    const float scale = (m==0) ? 0.09016844005556021f : 1.0f;  // log2e/16
    for (int idx = t; idx < 4096; idx += 256) {
        const float4 v4 = ((const float4*)W)[idx];
        const int c = idx >> 4;
        const int h = (idx & 15) * 4;
        wl[c][h+0]=v4.x*scale; wl[c][h+1]=v4.y*scale;
        wl[c][h+2]=v4.z*scale; wl[c][h+3]=v4.w*scale;
    }
    __syncthreads();
    const int h  = t & 63;
    const int n  = m*64 + h;
    const int c0 = (t >> 6) * 64;
    for (int c = c0; c < c0 + 64; c += 4) {
        ushort4 o;
        o.x=f2bf(wl[c+0][h]); o.y=f2bf(wl[c+1][h]);
        o.z=f2bf(wl[c+2][h]); o.w=f2bf(wl[c+3][h]);
        *(ushort4*)((char*)WtG + n*512 + ((c*2) ^ ((n&7)<<4))) = o;   // pre-swizzled
    }
}

// ---------------------------------------------------------------------------
// MFMA projection: q,k row-major bf16 + vT [b][h][T] bf16.
// W staged in LDS via linear global_load_lds (content pre-swizzled).
// ---------------------------------------------------------------------------
__global__ __launch_bounds__(256) void proj_mfma(
    const float* __restrict__ x, const ushort* __restrict__ WtG,
    ushort* __restrict__ qo, ushort* __restrict__ ko, ushort* __restrict__ vtG)
{
    __shared__ ushort xls[64*256];     // 32KB, swizzled 512B rows
    __shared__ ushort wls[192*256];    // 96KB, content pre-swizzled
    const int t = threadIdx.x, w = t>>6, lane = t&63, g = lane>>4, ln = lane&15;
    const int blk = blockIdx.x;
    const long rowbase = (long)blk * 64;
    const int b    = blk >> 6;
    const int trow = (blk & 63) * 64;

    {   // Wt: 96KB linear global->LDS copy (content already swizzled)
        const char* src = (const char*)WtG + (long)lane*16;
        for (int c = w; c < 96; c += 4)
            GLOAD16(src + c*1024, (char*)wls + c*1024);
    }
    for (int j = 0; j < 16; ++j) {
        const int idx = t + j*256;
        const int row = idx >> 6;
        const int c4  = (idx & 63) * 4;
        const float4 xv = ((const float4*)x)[(rowbase + row)*64 + (c4>>2)];
        ushort4 o; o.x=f2bf(xv.x); o.y=f2bf(xv.y); o.z=f2bf(xv.z); o.w=f2bf(xv.w);
        *(ushort4*)((char*)xls + swzx(row, c4*2)) = o;
    }
    __syncthreads();

    short8 xf[8];
    #pragma unroll
    for (int ks = 0; ks < 8; ++ks)
        xf[ks] = *(const short8*)((const char*)xls + swzx(w*16+ln, ks*64 + g*16));

    #pragma unroll
    for (int nt = 0; nt < 12; ++nt) {
        f32x4 acc = (f32x4){0.f,0.f,0.f,0.f};
        #pragma unroll
        for (int ks = 0; ks < 8; ++ks) {
            const short8 wf = *(const short8*)((const char*)wls + swzx(nt*16+ln, ks*64 + g*16));
            acc = (nt < 8) ? __builtin_amdgcn_mfma_f32_16x16x32_bf16(wf, xf[ks], acc, 0,0,0)
                           : __builtin_amdgcn_mfma_f32_16x16x32_bf16(xf[ks], wf, acc, 0,0,0);
        }
        ushort4 o; o.x=f2bf(acc[0]); o.y=f2bf(acc[1]); o.z=f2bf(acc[2]); o.w=f2bf(acc[3]);
        if (nt < 4) {
            *(ushort4*)(qo + (rowbase + w*16 + ln)*64 + nt*16 + g*4) = o;
        } else if (nt < 8) {
            *(ushort4*)(ko + (rowbase + w*16 + ln)*64 + (nt-4)*16 + g*4) = o;
        } else {
            *(ushort4*)(vtG + ((long)b*64 + (nt-8)*16 + ln)*T + trow + w*16 + g*4) = o;
        }
    }
}

// ---------------------------------------------------------------------------
// Flash attention, 32x32 swapped-QK^T, in-register softmax (no P LDS).
// Counted-vmcnt dbuf staging (T3/T4). VALU diet: truncation P-pack,
// max3-tree defer vote, truncation epilogue pack.
// Block = (b, qt[128 rows], chunk of <=4 key-tiles), 4 waves x 32 q-rows.
// grid = 4*272 = 1088, 256 thr.
// ---------------------------------------------------------------------------
__global__ __launch_bounds__(256) void attn_mfma(
    const ushort* __restrict__ q, const ushort* __restrict__ k,
    const ushort* __restrict__ vt,
    ushort* __restrict__ part_o, float* __restrict__ part_ml)
{
    __shared__ ushort kls[2][4096];      // K  [key][h], swizzled, dbuf (8KB ea)
    __shared__ ushort vtls[2][4096];     // V^T [h][key], swizzled, dbuf

    const int bid = blockIdx.x;
    const int b   = bid & 3;
    const int w2  = (CPB - 1) - (bid >> 2);        // big q-tiles first
    int qt = 0, c = 0;
    {
        int acc = 0;
        for (int qq = 0; qq < 32; ++qq) {
            const int n = (qq + 2) >> 1;
            if (w2 < acc + n) { qt = qq; c = w2 - acc; break; }
            acc += n;
        }
    }
    const int kt0   = c * 4;
    const int ktend = min(2*qt + 1, kt0 + 3);
    const int ntile = ktend - kt0 + 1;
    const int pid   = b*CPB + chunk_prefix(qt) + c;

    const int t = threadIdx.x, w = t>>6, lane = t&63;
    const int l5 = lane & 31, g5 = lane >> 5;
    const int lrow = lane >> 3;
    const int lc16 = ((lane & 7) ^ lrow) * 16;
    const char* kbase = (const char*)k  + ((long)b*T)*128;
    const char* vbase = (const char*)vt + ((long)b*64)*(long)T*2;

    // 4 gload_lds per wave per tile (2 K + 2 V) — vmcnt counting relies on this
    #define STAGE(bufi, ktile) do { \
        _Pragma("unroll") for (int j = 0; j < 2; ++j) { const int ci = w*2 + j; \
            GLOAD16(kbase + (long)(ktile)*8192 + ci*1024 + lrow*128 + lc16, \
                    (char*)kls[bufi] + ci*1024); \
            GLOAD16(vbase + ((long)(8*ci + lrow))*8192 + (long)(ktile)*128 + lc16, \
                    (char*)vtls[bufi] + ci*1024); \
        } } while(0)

    const int qmin = qt*128 + w*32;        // wave's first q row (in batch)
    const int qrow = qmin + l5;            // this lane's q row

    short8 qf[4];
    {
        const ushort* qp = q + ((long)(b*T + qrow))*64;
        #pragma unroll
        for (int hs = 0; hs < 4; ++hs)
            qf[hs] = *(const short8*)(qp + hs*16 + g5*8);
    }

    f32x16 o0, o1;                          // O^T acc: h-subtiles 0..31, 32..63
    #pragma unroll
    for (int i = 0; i < 16; ++i) { o0[i] = 0.f; o1[i] = 0.f; }
    float mrun = -INFINITY, lpart = 0.f;    // log2-domain m; per-lane l over own keys

    STAGE(0, kt0);
    for (int it = 0; it < ntile; ++it) {
        const int kt  = kt0 + it;
        const int cur = it & 1;

        // prefetch next tile, then wait ONLY for current buffer's 4 loads
        if (it + 1 < ntile) {
            STAGE(cur^1, kt + 1);
            asm volatile("s_waitcnt vmcnt(4)" ::: "memory");
        } else {
            asm volatile("s_waitcnt vmcnt(0)" ::: "memory");
        }
        __builtin_amdgcn_sched_barrier(0);
        __builtin_amdgcn_s_barrier();      // all waves: buf[cur] fully staged
        __builtin_amdgcn_sched_barrier(0);

        if (kt*64 <= qmin + 31) {          // wave not past diagonal
            // ---- S^T = K Q : D[key][q], two 32-key subtiles ----
            f32x16 s0, s1;
            #pragma unroll
            for (int i = 0; i < 16; ++i) { s0[i] = 0.f; s1[i] = 0.f; }
            __builtin_amdgcn_s_setprio(1);
            #pragma unroll
            for (int hs = 0; hs < 4; ++hs) {
                const short8 kf0 = *(const short8*)((const char*)kls[cur] + swzb(l5,    hs*32 + g5*16));
                s0 = __builtin_amdgcn_mfma_f32_32x32x16_bf16(kf0, qf[hs], s0, 0, 0, 0);
                const short8 kf1 = *(const short8*)((const char*)kls[cur] + swzb(32+l5, hs*32 + g5*16));
                s1 = __builtin_amdgcn_mfma_f32_32x32x16_bf16(kf1, qf[hs], s1, 0, 0, 0);
            }
            __builtin_amdgcn_s_setprio(0);

            if (kt*64 + 63 > qmin) {       // causal mask (diagonal region)
                #pragma unroll
                for (int reg = 0; reg < 16; ++reg) {
                    const int kl = (reg&3) + 8*(reg>>2) + 4*g5;
                    if (kt*64 + kl      > qrow) s0[reg] = -INFINITY;
                    if (kt*64 + 32 + kl > qrow) s1[reg] = -INFINITY;
                }
            }

            // ---- defer-max: lane tile-max via fmax tree (v_max3-fusable) ----
            float mt = fmaxf(s0[0], s1[0]);
            #pragma unroll
            for (int r = 1; r < 16; ++r)
                mt = fmaxf(mt, fmaxf(s0[r], s1[r]));
            if (!__all(mt <= mrun + 11.5f)) {   // rare: full reduce + rescale
                mt = fmaxf(mt, __shfl_xor(mt, 32));  // pair holds other 32 keys
                const float mn = fmaxf(mrun, mt);
                const float corr = fexp2(mrun - mn);  // 0 on first tile
                lpart *= corr;
                #pragma unroll
                for (int r = 0; r < 16; ++r) { o0[r] *= corr; o1[r] *= corr; }
                mrun = mn;
            }

            // ---- P = exp2(S - m), truncation-pack bf16 pairs ----
            unsigned u0[8], u1[8];
            #pragma unroll
            for (int i = 0; i < 8; ++i) {
                const float pa = fexp2(s0[2*i+0] - mrun);
                const float pb = fexp2(s0[2*i+1] - mrun);
                lpart += pa + pb;
                u0[i] = pkbf(pa, pb);
                const float pc = fexp2(s1[2*i+0] - mrun);
                const float pd = fexp2(s1[2*i+1] - mrun);
                lpart += pc + pd;
                u1[i] = pkbf(pc, pd);
            }
            // cross-half exchange: other lane's packs
            unsigned x0[8], x1[8];
            #pragma unroll
            for (int i = 0; i < 8; ++i) {
                x0[i] = (unsigned)__shfl_xor((int)u0[i], 32);
                x1[i] = (unsigned)__shfl_xor((int)u1[i], 32);
            }
            // assemble PV B-fragments: pfrag[ks2] covers keys ks2*16..+15
            int4v pw[4];
            #pragma unroll
            for (int s = 0; s < 2; ++s) {
                pw[s].x   = g5 ? (int)x0[4*s+2] : (int)u0[4*s+0];
                pw[s].y   = g5 ? (int)x0[4*s+3] : (int)u0[4*s+1];
                pw[s].z   = g5 ? (int)u0[4*s+2] : (int)x0[4*s+0];
                pw[s].w   = g5 ? (int)u0[4*s+3] : (int)x0[4*s+1];
                pw[2+s].x = g5 ? (int)x1[4*s+2] : (int)u1[4*s+0];
                pw[2+s].y = g5 ? (int)x1[4*s+3] : (int)u1[4*s+1];
                pw[2+s].z = g5 ? (int)u1[4*s+2] : (int)x1[4*s+0];
                pw[2+s].w = g5 ? (int)u1[4*s+3] : (int)x1[4*s+1];
            }

            // ---- O^T += V^T P : D[h][q] ----
            __builtin_amdgcn_s_setprio(1);
            #pragma unroll
            for (int ks2 = 0; ks2 < 4; ++ks2) {
                const short8 pa = __builtin_bit_cast(short8, pw[ks2]);
                const short8 vf0 = *(const short8*)((const char*)vtls[cur] + swzb(l5,    ks2*32 + g5*16));
                o0 = __builtin_amdgcn_mfma_f32_32x32x16_bf16(vf0, pa, o0, 0, 0, 0);
                const short8 vf1 = *(const short8*)((const char*)vtls[cur] + swzb(32+l5, ks2*32 + g5*16));
                o1 = __builtin_amdgcn_mfma_f32_32x32x16_bf16(vf1, pa, o1, 0, 0, 0);
            }
            __builtin_amdgcn_s_setprio(0);
        }

        __builtin_amdgcn_sched_barrier(0);
        __builtin_amdgcn_s_barrier();      // all reads of buf[cur] done before
        __builtin_amdgcn_sched_barrier(0); // next iter's STAGE overwrites it
    }
    #undef STAGE

    // ---- epilogue: pair-sum l, write (m,l) + O bf16 partials [q][h] ----
    const float ltot = lpart + __shfl_xor(lpart, 32);
    if (g5 == 0) {
        part_ml[((long)pid*128 + w*32 + l5)*2 + 0] = mrun;
        part_ml[((long)pid*128 + w*32 + l5)*2 + 1] = ltot;
    }
    // o0/o1 reg e of quad rq holds h = e + 8*rq + 4*g5 (o1: +32), q = w*32+l5
    ushort* po = part_o + (long)pid*8192 + (w*32 + l5)*64;
    #pragma unroll
    for (int rq = 0; rq < 4; ++rq) {
        uint2 a, bq;
        a.x  = pkbf(o0[4*rq+0], o0[4*rq+1]);
        a.y  = pkbf(o0[4*rq+2], o0[4*rq+3]);
        bq.x = pkbf(o1[4*rq+0], o1[4*rq+1]);
        bq.y = pkbf(o1[4*rq+2], o1[4*rq+3]);
        *(uint2*)(po + 8*rq + 4*g5)      = a;
        *(uint2*)(po + 32 + 8*rq + 4*g5) = bq;
    }
}

// ---------------------------------------------------------------------------
// Merge <=16 chunk partials (LSE, log2 domain), write fp32 [q][h] output.
// grid = (b, qt, 16q-slice) = 4*32*8 = 1024 blocks, 128 thr (2 waves, 8/CU).
// thread = (q-row 0..15, h-slice 0..7 of 8); wave reads 1KB contiguous/seg.
// ---------------------------------------------------------------------------
__global__ __launch_bounds__(128) void attn_merge(
    const ushort* __restrict__ part_o, const float* __restrict__ part_ml,
    float* __restrict__ out)
{
    const int bid = blockIdx.x;
    const int qs  = bid & 7;
    const int qt  = (bid >> 3) & 31;
    const int b   = bid >> 8;
    const int t   = threadIdx.x;
    const int ql  = qs*16 + (t >> 3);          // q_local 0..127
    const int hs  = t & 7;                      // 8-wide h slice
    const int nseg = (qt + 2) >> 1;
    const int base = b*CPB + chunk_prefix(qt);

    float mstar = -INFINITY;
    for (int s = 0; s < nseg; ++s)
        mstar = fmaxf(mstar, part_ml[((long)(base+s)*128 + ql)*2]);

    float acc[8];
    #pragma unroll
    for (int i = 0; i < 8; ++i) acc[i] = 0.f;
    float lsum = 0.f;
    #pragma unroll 2
    for (int s = 0; s < nseg; ++s) {
        const float2 ml = *(const float2*)(part_ml + ((long)(base+s)*128 + ql)*2);
        const float wgt = fexp2(ml.x - mstar);
        lsum += ml.y * wgt;
        const short8 v8 = *(const short8*)(part_o + (long)(base+s)*8192 + ql*64 + hs*8);
        #pragma unroll
        for (int e = 0; e < 8; ++e)
            acc[e] += wgt * bf2f((ushort)v8[e]);
    }
    const float inv = 1.f / lsum;
    float* op = out + ((long)b*T + qt*128 + ql)*64 + hs*8;
    ((float4*)op)[0] = make_float4(acc[0]*inv, acc[1]*inv, acc[2]*inv, acc[3]*inv);
    ((float4*)op)[1] = make_float4(acc[4]*inv, acc[5]*inv, acc[6]*inv, acc[7]*inv);
}

// ---------------------------------------------------------------------------
extern "C" void kernel_launch(void* const* d_in, const int* in_sizes, int n_in,
                              void* d_out, int out_size, void* d_ws, size_t ws_size,
                              hipStream_t stream)
{
    const float* x  = (const float*)d_in[0];
    const float* Wk = (const float*)d_in[1];
    const float* Wq = (const float*)d_in[2];
    const float* Wv = (const float*)d_in[3];

    char* w8 = (char*)d_ws;
    ushort* qb      = (ushort*)(w8);                    // 2 MB
    ushort* kb      = (ushort*)(w8 + (2l<<20));         // 2 MB
    ushort* vt      = (ushort*)(w8 + (4l<<20));         // 2 MB
    ushort* Wt      = (ushort*)(w8 + (6l<<20));         // 96 KB
    ushort* part_o  = (ushort*)(w8 + (7l<<20));         // 1088*16KB = 17.4 MB
    float*  part_ml = (float*) (w8 + (25l<<20));        // 1.1 MB

    wtrans    <<<3,         256, 0, stream>>>(Wq, Wk, Wv, Wt);
    proj_mfma <<<BT/64,     256, 0, stream>>>(x, Wt, qb, kb, vt);
    attn_mfma <<<Bb*CPB,    256, 0, stream>>>(qb, kb, vt, part_o, part_ml);
    attn_merge<<<Bb*32*8,   128, 0, stream>>>(part_o, part_ml, (float*)d_out);
}